// Round 14
// baseline (200.123 us; speedup 1.0000x reference)
//
#include <hip/hip_runtime.h>
#include <math.h>

// Denoiser via hop-aligned DFT factorization (N=1024, HOP=256 -> 4 segments):
//   T_k(g)  = sum_{h<256} x[g*256+h] e^{-i*th*k*h}          (GEMM-T, K=256)
//   X_k(f)  = sum_d (-i)^{dk} T_k(f+d)                      (elemA, adds only)
//   Xw_k    = 0.5 X_k - 0.25(X_{k-1}+X_{k+1})               (hann in freq)
//   Z_k     = nonlin(Xw_k)                                  (elemA)
//   Z'_k    = 0.5 Z_k - 0.25(Z_{k-1}+Z_{k+1})               (synth window)
//   C_k(g)  = sum_d i^{dk} Z'_k(g-d), frames outside [0,4097) zero  (elemB)
//   out[g*256+h] = (1/ws) sum_k d_k [Cre cos(th k h) - Cim sin(th k h)] (GEMM-C)
// Channel map everywhere: ch<513 = re_k ; ch=512+k = im_k (k=1..511).
//
// Workspace (bytes):
//   fwdT  @ 0          : 1024*256*2  = 0.5 MB
//   invT2 @ 524,288    : 256*1024*2  = 0.5 MB
//   aud   @ 1,048,576  : 4*1,082,368*2 = 8.66 MB
//   T     @ 9,707,520  : 4*4224*1024*2 = 34.6 MB
//   Z     @ 44,310,528 : 4*4100*1024*2 = 33.6 MB
//   C     @ 77,897,728 : 4*4096*1024*2 = 33.6 MB   (ends ~111.5 MB)

#define NFFT 1024
#define HOP  256
#define CUT  513
#define NB   4
#define LAUD 1048576
#define NFR  4097      // valid frames
#define NSEG 4224      // T rows per batch (33 tiles of 128)
#define NZROW 4100     // Z row stride region per batch
#define NCOL 4096      // C rows per batch = output segments (g-2)
#define ABLEN 1082368

typedef __attribute__((ext_vector_type(4))) float f32x4;
typedef __attribute__((ext_vector_type(8))) short bf16x8;

#define AS1 __attribute__((address_space(1)))
#define AS3 __attribute__((address_space(3)))

__device__ __forceinline__ unsigned short f2bf(float x) {
    unsigned u = __float_as_uint(x);
    u += 0x7FFF + ((u >> 16) & 1);   // RNE
    return (unsigned short)(u >> 16);
}
__device__ __forceinline__ float bf2f(unsigned short h) {
    return __uint_as_float(((unsigned)h) << 16);
}

// ---- K1: small bases --------------------------------------------------------
__global__ __launch_bounds__(256) void build_bases_k(
    ushort* __restrict__ fwdT, ushort* __restrict__ invT2) {
    __shared__ float ctab[1024];
    const int tid = threadIdx.x, bx = blockIdx.x;   // grid 1024
    const float CST = 6.135923151542565e-3f;        // 2*pi/1024
    #pragma unroll
    for (int i = 0; i < 4; ++i) ctab[(i << 8) + tid] = cosf(CST * (float)((i << 8) + tid));
    __syncthreads();
    int idx = (bx << 8) + tid;                      // [0, 262144)
    {   // fwdT[ch][h] : re -> cos, im -> -sin
        int ch = idx >> 8, h = idx & 255;
        int k = (ch < CUT) ? ch : ch - 512;
        int m = (k * h) & 1023;
        float base = (ch < CUT) ? ctab[m] : -ctab[(m + 768) & 1023];
        fwdT[idx] = f2bf(base);
    }
    {   // invT2[h][ch] : d_k * (re -> cos, im -> -sin)
        int h = idx >> 10, ch = idx & 1023;
        int k = (ch < CUT) ? ch : ch - 512;
        int m = (k * h) & 1023;
        float base = (ch < CUT) ? ctab[m] : -ctab[(m + 768) & 1023];
        float d = (k == 0 || k == 512) ? (1.0f / 1024.0f) : (2.0f / 1024.0f);
        invT2[idx] = f2bf(base * d);
    }
}

// ---- K2: pad+cast audio -----------------------------------------------------
__global__ void cvt_audio_k(const float* __restrict__ audio, ushort* __restrict__ aud) {
    const int NV = ABLEN / 8;                      // 135296
    int idx = blockIdx.x * blockDim.x + threadIdx.x;
    if (idx >= NB * NV) return;
    int b = idx / NV;
    int t8 = (idx - b * NV) << 3;
    const float* ap = audio + (long)b * LAUD;
    ushort o[8];
    int j0 = t8 - 512;
    if (j0 >= 0 && j0 + 7 < LAUD) {
        f32x4 v0 = *(const f32x4*)(ap + j0);
        f32x4 v1 = *(const f32x4*)(ap + j0 + 4);
        #pragma unroll
        for (int q = 0; q < 4; ++q) { o[q] = f2bf(v0[q]); o[4 + q] = f2bf(v1[q]); }
    } else {
        #pragma unroll
        for (int q = 0; q < 8; ++q) {
            int t = t8 + q;
            float v = 0.f;
            if (t < LAUD + 1024) {
                int j = t - 512;
                if (j < 0) j = -j;
                if (j >= LAUD) j = 2 * LAUD - 2 - j;
                v = ap[j];
            }
            o[q] = f2bf(v);
        }
    }
    *(ushort4*)(aud + (long)b * ABLEN + t8)     = *(ushort4*)&o[0];
    *(ushort4*)(aud + (long)b * ABLEN + t8 + 4) = *(ushort4*)&o[4];
}

// ---- K3: GEMM-T (M=1024 ch, K=256, N=4224 segs) -- proven R7 structure ------
__global__ __launch_bounds__(256) void gemm_t_k(
    const ushort* __restrict__ fwdT, const ushort* __restrict__ aud,
    ushort* __restrict__ T) {
    __shared__ char smem[32768];
    const int tid = threadIdx.x;
    const int wid = tid >> 6, lane = tid & 63;
    const int lh = lane & 15, lg = lane >> 4;
    const int wm = wid >> 1, wn = wid & 1;
    int w = (blockIdx.x & 7) * 132 + (blockIdx.x >> 3);   // 1056 = 8*132
    const int f0 = (w % 33) << 7;
    const int c0 = ((w / 33) & 7) << 7;
    const int b  = w / 264;
    const ushort* ab = aud + (long)b * ABLEN;
    f32x4 acc[4][4] = {};

    for (int k0 = 0; k0 < 256; k0 += 64) {
        if (k0) __syncthreads();
        #pragma unroll
        for (int i = 0; i < 4; ++i) {
            int ci = (i << 8) + tid;
            int row = ci >> 3;
            int ks = k0 + (((ci & 7) ^ (row & 7)) << 3);
            __builtin_amdgcn_global_load_lds(
                (const AS1 unsigned int*)(fwdT + ((c0 + row) << 8) + ks),
                (AS3 unsigned int*)(smem + (i << 12) + (wid << 10)), 16, 0, 0);
            __builtin_amdgcn_global_load_lds(
                (const AS1 unsigned int*)(ab + (f0 + row) * 256 + ks),
                (AS3 unsigned int*)(smem + 16384 + (i << 12) + (wid << 10)), 16, 0, 0);
        }
        __syncthreads();
        #pragma unroll
        for (int s = 0; s < 2; ++s) {
            bf16x8 av[4], bv[4];
            #pragma unroll
            for (int i = 0; i < 4; ++i) {
                int r = (wm << 6) + (i << 4) + lh;
                av[i] = *(const bf16x8*)(smem + (r << 7) + ((((s << 2) + lg) ^ (r & 7)) << 4));
                int q = (wn << 6) + (i << 4) + lh;
                bv[i] = *(const bf16x8*)(smem + 16384 + (q << 7) + ((((s << 2) + lg) ^ (q & 7)) << 4));
            }
            #pragma unroll
            for (int i = 0; i < 4; ++i)
                #pragma unroll
                for (int j = 0; j < 4; ++j)
                    acc[i][j] = __builtin_amdgcn_mfma_f32_16x16x32_bf16(av[i], bv[j], acc[i][j], 0, 0, 0);
        }
    }
    ushort* Tb = T + (long)b * NSEG * 1024;
    #pragma unroll
    for (int i = 0; i < 4; ++i) {
        int c = c0 + (wm << 6) + (i << 4) + (lg << 2);
        #pragma unroll
        for (int j = 0; j < 4; ++j) {
            int g = f0 + (wn << 6) + (j << 4) + lh;
            ushort4 o;
            o.x = f2bf(acc[i][j][0]); o.y = f2bf(acc[i][j][1]);
            o.z = f2bf(acc[i][j][2]); o.w = f2bf(acc[i][j][3]);
            *(ushort4*)(Tb + ((long)g << 10) + c) = o;
        }
    }
}

// ---- elemA: 4-segment combine + analysis window + nonlin -> Z ---------------
__device__ __forceinline__ float2 combineX(const ushort* __restrict__ Tr, int m) {
    bool cj = false;
    if (m < 0) { m = -m; cj = true; }
    else if (m > 512) { m = 1024 - m; cj = true; }
    float a[4], bb[4];
    #pragma unroll
    for (int d = 0; d < 4; ++d) {
        a[d]  = bf2f(Tr[(d << 10) + m]);
        bb[d] = (m >= 1 && m <= 511) ? bf2f(Tr[(d << 10) + 512 + m]) : 0.f;
    }
    int r = m & 3;
    float xr, xi;
    if      (r == 0) { xr = a[0] + a[1] + a[2] + a[3];   xi = bb[0] + bb[1] + bb[2] + bb[3]; }
    else if (r == 1) { xr = a[0] + bb[1] - a[2] - bb[3]; xi = bb[0] - a[1] - bb[2] + a[3]; }
    else if (r == 2) { xr = a[0] - a[1] + a[2] - a[3];   xi = bb[0] - bb[1] + bb[2] - bb[3]; }
    else             { xr = a[0] - bb[1] - a[2] + bb[3]; xi = bb[0] + a[1] - bb[2] - a[3]; }
    float2 res; res.x = xr; res.y = cj ? -xi : xi;
    return res;
}

__device__ __forceinline__ void nonlin_store(const ushort* Tr, const float* bias,
                                             ushort* Zr, int k) {
    float2 xm = combineX(Tr, k - 1);
    float2 x0 = combineX(Tr, k);
    float2 xp = combineX(Tr, k + 1);
    float xwr = 0.5f * x0.x - 0.25f * (xm.x + xp.x);
    float xwi = 0.5f * x0.y - 0.25f * (xm.y + xp.y);
    float mag = sqrtf(xwr * xwr + xwi * xwi);
    float s = mag > 0.f ? fmaxf(mag - 0.1f * bias[k], 0.f) / mag : 0.f;
    Zr[k] = f2bf(xwr * s);
    if (k >= 1 && k <= 511) Zr[512 + k] = f2bf(xwi * s);
}

__global__ __launch_bounds__(256) void elem_a_k(
    const ushort* __restrict__ T, const float* __restrict__ bias,
    ushort* __restrict__ Z) {
    int bid = blockIdx.x;                 // NB*NFR
    int b = bid / NFR, f = bid - b * NFR;
    const ushort* Tr = T + ((long)(b * NSEG + f) << 10);
    ushort* Zr = Z + ((long)(b * NZROW + f) << 10);
    int tid = threadIdx.x;
    nonlin_store(Tr, bias, Zr, tid);
    nonlin_store(Tr, bias, Zr, tid + 256);
    if (tid == 0) nonlin_store(Tr, bias, Zr, 512);
}

// ---- elemB: synthesis window + i^{dk} frame combination -> C ----------------
__device__ __forceinline__ float2 loadZ(const ushort* __restrict__ Zr, int m) {
    bool cj = false;
    if (m < 0) { m = -m; cj = true; }
    else if (m > 512) { m = 1024 - m; cj = true; }
    float zr = bf2f(Zr[m]);
    float zi = (m >= 1 && m <= 511) ? bf2f(Zr[512 + m]) : 0.f;
    float2 res; res.x = zr; res.y = cj ? -zi : zi;
    return res;
}

__device__ __forceinline__ void comb_store(const ushort* Zb, ushort* Cr, int g, int k) {
    int r = k & 3;
    float cr = 0.f, ci = 0.f;
    #pragma unroll
    for (int d = 0; d < 4; ++d) {
        int f = g - d;
        if (f < 0 || f >= NFR) continue;
        const ushort* Zr = Zb + ((long)f << 10);
        float2 zm = loadZ(Zr, k - 1);
        float2 z0 = loadZ(Zr, k);
        float2 zp = loadZ(Zr, k + 1);
        float ar = 0.5f * z0.x - 0.25f * (zm.x + zp.x);
        float ai = 0.5f * z0.y - 0.25f * (zm.y + zp.y);
        int rd = (d * r) & 3;        // i^{dk} = i^{(d*(k&3)) & 3}
        float er, ei;
        if      (rd == 0) { er = ar;  ei = ai; }
        else if (rd == 1) { er = -ai; ei = ar; }
        else if (rd == 2) { er = -ar; ei = -ai; }
        else              { er = ai;  ei = -ar; }
        cr += er; ci += ei;
    }
    Cr[k] = f2bf(cr);
    if (k >= 1 && k <= 511) Cr[512 + k] = f2bf(ci);
}

__global__ __launch_bounds__(256) void elem_b_k(
    const ushort* __restrict__ Z, ushort* __restrict__ C) {
    int bid = blockIdx.x;                 // NB*NCOL, NCOL = 4096
    int b = bid >> 12, j = bid & 4095;
    int g = j + 2;
    const ushort* Zb = Z + (long)b * NZROW * 1024;
    ushort* Cr = C + ((long)(b * NCOL + j) << 10);
    int tid = threadIdx.x;
    comb_store(Zb, Cr, g, tid);
    comb_store(Zb, Cr, g, tid + 256);
    if (tid == 0) comb_store(Zb, Cr, g, 512);
}

// ---- K6: GEMM-C (M=256 h, K=1024 ch, N=4096 segs) -- proven split-K ---------
__global__ __launch_bounds__(512) void gemm_c_k(
    const ushort* __restrict__ invT2, const ushort* __restrict__ C,
    float* __restrict__ out) {
    __shared__ char smem[49152];
    const int tid = threadIdx.x;
    const int wid = tid >> 6, lane = tid & 63;
    const int lh = lane & 15, lg = lane >> 4;
    const int g = wid >> 2;           // K-group
    const int wid2 = wid & 3;
    const int wm = wid2 >> 1, wn = wid2 & 1;
    const int tg = tid & 255;
    int w = (blockIdx.x & 7) * 64 + (blockIdx.x >> 3);    // 512 = 8*64
    const int h0  = (w & 1) << 7;
    const int j0  = ((w >> 1) & 63) << 6;
    const int fo0 = 2 + j0;
    const int b   = w >> 7;
    const ushort* Cb = C + (long)b * NCOL * 1024;
    char* sm = smem + g * 24576;
    f32x4 acc[4][2] = {};

    for (int k0s = 0; k0s < 512; k0s += 64) {
        if (k0s) __syncthreads();
        int kk = (g << 9) + k0s;
        #pragma unroll
        for (int i = 0; i < 4; ++i) {  // A: invT2 rows h0..h0+127
            int ci = (i << 8) + tg;
            int row = ci >> 3;
            int swz = (((ci & 7) ^ (row & 7)) << 3);
            __builtin_amdgcn_global_load_lds(
                (const AS1 unsigned int*)(invT2 + ((h0 + row) << 10) + kk + swz),
                (AS3 unsigned int*)(sm + (i << 12) + (wid2 << 10)), 16, 0, 0);
        }
        #pragma unroll
        for (int i = 0; i < 2; ++i) {  // B: C rows j0..j0+63
            int ci = (i << 8) + tg;
            int row = ci >> 3;
            int swz = (((ci & 7) ^ (row & 7)) << 3);
            __builtin_amdgcn_global_load_lds(
                (const AS1 unsigned int*)(Cb + ((long)(j0 + row) << 10) + kk + swz),
                (AS3 unsigned int*)(sm + 16384 + (i << 12) + (wid2 << 10)), 16, 0, 0);
        }
        __syncthreads();
        #pragma unroll
        for (int s = 0; s < 2; ++s) {
            bf16x8 av[4], bv[2];
            #pragma unroll
            for (int i = 0; i < 4; ++i) {
                int r = (wm << 6) + (i << 4) + lh;
                av[i] = *(const bf16x8*)(sm + (r << 7) + ((((s << 2) + lg) ^ (r & 7)) << 4));
            }
            #pragma unroll
            for (int j = 0; j < 2; ++j) {
                int rq = (wn << 5) + (j << 4) + lh;
                bv[j] = *(const bf16x8*)(sm + 16384 + (rq << 7) + ((((s << 2) + lg) ^ (rq & 7)) << 4));
            }
            #pragma unroll
            for (int i = 0; i < 4; ++i)
                #pragma unroll
                for (int j = 0; j < 2; ++j)
                    acc[i][j] = __builtin_amdgcn_mfma_f32_16x16x32_bf16(av[i], bv[j], acc[i][j], 0, 0, 0);
        }
    }
    __syncthreads();
    float* red = (float*)smem;
    if (g == 1) {
        #pragma unroll
        for (int i = 0; i < 4; ++i)
            #pragma unroll
            for (int j = 0; j < 2; ++j) {
                int hl = (wm << 6) + (i << 4) + (lg << 2);
                int fl = (wn << 5) + (j << 4) + lh;
                #pragma unroll
                for (int q = 0; q < 4; ++q)
                    red[(hl + q) * 64 + fl] = acc[i][j][q];
            }
    }
    __syncthreads();
    if (g == 1) return;
    float* ob = out + (long)b * LAUD;
    const float CST = 6.135923151542565e-3f;
    #pragma unroll
    for (int i = 0; i < 4; ++i) {
        int hbase = h0 + (wm << 6) + (i << 4) + (lg << 2);
        int hl = (wm << 6) + (i << 4) + (lg << 2);
        #pragma unroll
        for (int j = 0; j < 2; ++j) {
            int fo = fo0 + (wn << 5) + (j << 4) + lh;
            int fl = (wn << 5) + (j << 4) + lh;
            f32x4 v = acc[i][j];
            #pragma unroll
            for (int q = 0; q < 4; ++q) v[q] += red[(hl + q) * 64 + fl];
            if (fo == 2 || fo == 4097) {       // edge window-sum (missing frame)
                #pragma unroll
                for (int q = 0; q < 4; ++q) {
                    int n = (fo == 2) ? (hbase + q + 768) : (hbase + q);
                    float w2 = 0.5f - 0.5f * cosf(CST * (float)n);
                    v[q] = v[q] * (1.0f / (1.5f - w2 * w2));
                }
            } else {
                v *= (2.0f / 3.0f);            // 0.25 * 4 / ws, ws = 1.5
            }
            *(f32x4*)(ob + (((long)(fo - 2)) << 8) + hbase) = v;
        }
    }
}

extern "C" void kernel_launch(void* const* d_in, const int* in_sizes, int n_in,
                              void* d_out, int out_size, void* d_ws, size_t ws_size,
                              hipStream_t stream) {
    const float* audio = (const float*)d_in[0];
    const float* bias  = (const float*)d_in[1];
    float* out = (float*)d_out;
    char* wsb = (char*)d_ws;

    ushort* fwdT  = (ushort*)(wsb);
    ushort* invT2 = (ushort*)(wsb + 524288);
    ushort* aud   = (ushort*)(wsb + 1048576);
    ushort* T     = (ushort*)(wsb + 9707520);
    ushort* Z     = (ushort*)(wsb + 44310528);
    ushort* C     = (ushort*)(wsb + 77897728);

    build_bases_k<<<1024, 256, 0, stream>>>(fwdT, invT2);

    int cvt_total = NB * (ABLEN / 8);
    cvt_audio_k<<<(cvt_total + 255) / 256, 256, 0, stream>>>(audio, aud);

    gemm_t_k<<<1056, 256, 0, stream>>>(fwdT, aud, T);

    elem_a_k<<<NB * NFR, 256, 0, stream>>>(T, bias, Z);

    elem_b_k<<<NB * NCOL, 256, 0, stream>>>(Z, C);

    gemm_c_k<<<512, 512, 0, stream>>>(invT2, C, out);
}

// Round 15
// 116.234 us; speedup vs baseline: 1.7217x; 1.7217x over previous
//
#include <hip/hip_runtime.h>
#include <math.h>

// Denoiser via hop-aligned DFT factorization (N=1024, HOP=256 -> 4 segments):
//   T_k(g)  = sum_{h<256} x[g*256+h] e^{-i*th*k*h}          (GEMM-T, K=256)
//   X_k(f)  = sum_d (-i)^{dk} T_k(f+d)                      (elemA)
//   Xw_k    = 0.5 X_k - 0.25(X_{k-1}+X_{k+1})               (hann in freq)
//   Z_k     = nonlin(Xw_k);  Z'_k = 0.5 Z_k - 0.25(Z_{k-1}+Z_{k+1})  (elemA)
//   C_k(g)  = sum_d i^{dk} Z'_k(g-d), frames outside [0,4097) zero   (elemB)
//   out[g*256+h] = (1/ws) sum_k d_k [Cre cos(th k h) - Cim sin(th k h)] (GEMM-C)
// Channel map everywhere: ch<513 = re_k ; ch=512+k = im_k (k=1..511).
//
// Workspace (bytes):
//   fwdT  @ 0          : 1024*256*2  = 0.5 MB
//   invT2 @ 524,288    : 256*1024*2  = 0.5 MB
//   aud   @ 1,048,576  : 4*1,082,368*2 = 8.66 MB
//   T     @ 9,707,520  : 4*4224*1024*2 = 34.6 MB
//   Z     @ 44,310,528 : 4*4100*1024*2 = 33.6 MB   (holds Z')
//   C     @ 77,897,728 : 4*4096*1024*2 = 33.6 MB   (ends ~111.5 MB)

#define NFFT 1024
#define HOP  256
#define CUT  513
#define NB   4
#define LAUD 1048576
#define NFR  4097      // valid frames
#define NSEG 4224      // T rows per batch
#define NZROW 4100     // Z row region per batch
#define NCOL 4096      // C rows per batch = output segments (g-2)
#define ABLEN 1082368

typedef __attribute__((ext_vector_type(4))) float f32x4;
typedef __attribute__((ext_vector_type(8))) short bf16x8;

#define AS1 __attribute__((address_space(1)))
#define AS3 __attribute__((address_space(3)))

__device__ __forceinline__ unsigned short f2bf(float x) {
    unsigned u = __float_as_uint(x);
    u += 0x7FFF + ((u >> 16) & 1);   // RNE
    return (unsigned short)(u >> 16);
}
__device__ __forceinline__ float bf2f(unsigned short h) {
    return __uint_as_float(((unsigned)h) << 16);
}

// ---- K1: small bases --------------------------------------------------------
__global__ __launch_bounds__(256) void build_bases_k(
    ushort* __restrict__ fwdT, ushort* __restrict__ invT2) {
    __shared__ float ctab[1024];
    const int tid = threadIdx.x, bx = blockIdx.x;   // grid 1024
    const float CST = 6.135923151542565e-3f;        // 2*pi/1024
    #pragma unroll
    for (int i = 0; i < 4; ++i) ctab[(i << 8) + tid] = cosf(CST * (float)((i << 8) + tid));
    __syncthreads();
    int idx = (bx << 8) + tid;                      // [0, 262144)
    {   // fwdT[ch][h] : re -> cos, im -> -sin
        int ch = idx >> 8, h = idx & 255;
        int k = (ch < CUT) ? ch : ch - 512;
        int m = (k * h) & 1023;
        float base = (ch < CUT) ? ctab[m] : -ctab[(m + 768) & 1023];
        fwdT[idx] = f2bf(base);
    }
    {   // invT2[h][ch] : d_k * (re -> cos, im -> -sin)
        int h = idx >> 10, ch = idx & 1023;
        int k = (ch < CUT) ? ch : ch - 512;
        int m = (k * h) & 1023;
        float base = (ch < CUT) ? ctab[m] : -ctab[(m + 768) & 1023];
        float d = (k == 0 || k == 512) ? (1.0f / 1024.0f) : (2.0f / 1024.0f);
        invT2[idx] = f2bf(base * d);
    }
}

// ---- K2: pad+cast audio -----------------------------------------------------
__global__ void cvt_audio_k(const float* __restrict__ audio, ushort* __restrict__ aud) {
    const int NV = ABLEN / 8;                      // 135296
    int idx = blockIdx.x * blockDim.x + threadIdx.x;
    if (idx >= NB * NV) return;
    int b = idx / NV;
    int t8 = (idx - b * NV) << 3;
    const float* ap = audio + (long)b * LAUD;
    ushort o[8];
    int j0 = t8 - 512;
    if (j0 >= 0 && j0 + 7 < LAUD) {
        f32x4 v0 = *(const f32x4*)(ap + j0);
        f32x4 v1 = *(const f32x4*)(ap + j0 + 4);
        #pragma unroll
        for (int q = 0; q < 4; ++q) { o[q] = f2bf(v0[q]); o[4 + q] = f2bf(v1[q]); }
    } else {
        #pragma unroll
        for (int q = 0; q < 8; ++q) {
            int t = t8 + q;
            float v = 0.f;
            if (t < LAUD + 1024) {
                int j = t - 512;
                if (j < 0) j = -j;
                if (j >= LAUD) j = 2 * LAUD - 2 - j;
                v = ap[j];
            }
            o[q] = f2bf(v);
        }
    }
    *(ushort4*)(aud + (long)b * ABLEN + t8)     = *(ushort4*)&o[0];
    *(ushort4*)(aud + (long)b * ABLEN + t8 + 4) = *(ushort4*)&o[4];
}

// ---- K3: GEMM-T (M=1024 ch, K=256, N=4224 segs) -----------------------------
__global__ __launch_bounds__(256) void gemm_t_k(
    const ushort* __restrict__ fwdT, const ushort* __restrict__ aud,
    ushort* __restrict__ T) {
    __shared__ char smem[32768];
    const int tid = threadIdx.x;
    const int wid = tid >> 6, lane = tid & 63;
    const int lh = lane & 15, lg = lane >> 4;
    const int wm = wid >> 1, wn = wid & 1;
    int w = (blockIdx.x & 7) * 132 + (blockIdx.x >> 3);   // 1056 = 8*132
    const int f0 = (w % 33) << 7;
    const int c0 = ((w / 33) & 7) << 7;
    const int b  = w / 264;
    const ushort* ab = aud + (long)b * ABLEN;
    f32x4 acc[4][4] = {};

    for (int k0 = 0; k0 < 256; k0 += 64) {
        if (k0) __syncthreads();
        #pragma unroll
        for (int i = 0; i < 4; ++i) {
            int ci = (i << 8) + tid;
            int row = ci >> 3;
            int ks = k0 + (((ci & 7) ^ (row & 7)) << 3);
            __builtin_amdgcn_global_load_lds(
                (const AS1 unsigned int*)(fwdT + ((c0 + row) << 8) + ks),
                (AS3 unsigned int*)(smem + (i << 12) + (wid << 10)), 16, 0, 0);
            __builtin_amdgcn_global_load_lds(
                (const AS1 unsigned int*)(ab + (f0 + row) * 256 + ks),
                (AS3 unsigned int*)(smem + 16384 + (i << 12) + (wid << 10)), 16, 0, 0);
        }
        __syncthreads();
        #pragma unroll
        for (int s = 0; s < 2; ++s) {
            bf16x8 av[4], bv[4];
            #pragma unroll
            for (int i = 0; i < 4; ++i) {
                int r = (wm << 6) + (i << 4) + lh;
                av[i] = *(const bf16x8*)(smem + (r << 7) + ((((s << 2) + lg) ^ (r & 7)) << 4));
                int q = (wn << 6) + (i << 4) + lh;
                bv[i] = *(const bf16x8*)(smem + 16384 + (q << 7) + ((((s << 2) + lg) ^ (q & 7)) << 4));
            }
            #pragma unroll
            for (int i = 0; i < 4; ++i)
                #pragma unroll
                for (int j = 0; j < 4; ++j)
                    acc[i][j] = __builtin_amdgcn_mfma_f32_16x16x32_bf16(av[i], bv[j], acc[i][j], 0, 0, 0);
        }
    }
    ushort* Tb = T + (long)b * NSEG * 1024;
    #pragma unroll
    for (int i = 0; i < 4; ++i) {
        int c = c0 + (wm << 6) + (i << 4) + (lg << 2);
        #pragma unroll
        for (int j = 0; j < 4; ++j) {
            int g = f0 + (wn << 6) + (j << 4) + lh;
            ushort4 o;
            o.x = f2bf(acc[i][j][0]); o.y = f2bf(acc[i][j][1]);
            o.z = f2bf(acc[i][j][2]); o.w = f2bf(acc[i][j][3]);
            *(ushort4*)(Tb + ((long)g << 10) + c) = o;
        }
    }
}

// ---- elemA: combine + window + nonlin + synth window -> Z' (LDS-staged) -----
__global__ __launch_bounds__(256) void elem_a_k(
    const ushort* __restrict__ T, const float* __restrict__ bias,
    ushort* __restrict__ Z) {
    __shared__ ushort Tl[4096];          // rows f..f+3
    __shared__ float Xr[513], Xi[513];
    __shared__ float Zr_[513], Zi_[513];
    int bid = blockIdx.x;                // NB*NFR
    int b = bid / NFR, f = bid - b * NFR;
    const ushort* Tr = T + ((long)(b * NSEG + f) << 10);
    ushort* Zo = Z + ((long)(b * NZROW + f) << 10);
    const int tid = threadIdx.x;

    ((uint4*)Tl)[tid]       = ((const uint4*)Tr)[tid];        // 8KB vectorized
    ((uint4*)Tl)[tid + 256] = ((const uint4*)Tr)[tid + 256];
    __syncthreads();

    // X_k = sum_d (-i)^{dk} T_k(f+d), k in [0,512]
    #pragma unroll
    for (int half = 0; half < 2; ++half) {
        int k = (half << 8) + tid;
        if (k > 512) continue;
        float a[4], bb[4];
        #pragma unroll
        for (int d = 0; d < 4; ++d) {
            a[d]  = bf2f(Tl[(d << 10) + k]);
            bb[d] = (k >= 1 && k <= 511) ? bf2f(Tl[(d << 10) + 512 + k]) : 0.f;
        }
        int r = k & 3;
        float xr, xi;
        if      (r == 0) { xr = a[0] + a[1] + a[2] + a[3];   xi = bb[0] + bb[1] + bb[2] + bb[3]; }
        else if (r == 1) { xr = a[0] + bb[1] - a[2] - bb[3]; xi = bb[0] - a[1] - bb[2] + a[3]; }
        else if (r == 2) { xr = a[0] - a[1] + a[2] - a[3];   xi = bb[0] - bb[1] + bb[2] - bb[3]; }
        else             { xr = a[0] - bb[1] - a[2] + bb[3]; xi = bb[0] + a[1] - bb[2] - a[3]; }
        Xr[k] = xr; Xi[k] = xi;
    }
    if (tid == 0) {   // k = 512 (tid pattern covers 0..511)
        float a[4];
        #pragma unroll
        for (int d = 0; d < 4; ++d) a[d] = bf2f(Tl[(d << 10) + 512]);
        Xr[512] = a[0] - a[1] + a[2] - a[3];  // r=0 pattern? 512&3=0 -> all +
        Xr[512] = a[0] + a[1] + a[2] + a[3];
        Xi[512] = 0.f;
    }
    __syncthreads();

    // Zw = window(X); Z = nonlin(Zw)
    #pragma unroll
    for (int half = 0; half < 3; ++half) {
        int k = (half < 2) ? (half << 8) + tid : 512;
        if (half == 2 && tid != 0) continue;
        if (k > 512) continue;
        int km = k - 1, kp = k + 1;
        float smr, smi, spr, spi;
        if (km < 0) { smr = Xr[1];  smi = -Xi[1]; }  else { smr = Xr[km]; smi = Xi[km]; }
        if (kp > 512) { spr = Xr[511]; spi = -Xi[511]; } else { spr = Xr[kp]; spi = Xi[kp]; }
        float xwr = 0.5f * Xr[k] - 0.25f * (smr + spr);
        float xwi = 0.5f * Xi[k] - 0.25f * (smi + spi);
        float mag = sqrtf(xwr * xwr + xwi * xwi);
        float s = mag > 0.f ? fmaxf(mag - 0.1f * bias[k], 0.f) / mag : 0.f;
        Zr_[k] = xwr * s; Zi_[k] = xwi * s;
    }
    __syncthreads();

    // Z' = window(Z), store bf16
    #pragma unroll
    for (int half = 0; half < 3; ++half) {
        int k = (half < 2) ? (half << 8) + tid : 512;
        if (half == 2 && tid != 0) continue;
        if (k > 512) continue;
        int km = k - 1, kp = k + 1;
        float smr, smi, spr, spi;
        if (km < 0) { smr = Zr_[1];  smi = -Zi_[1]; }  else { smr = Zr_[km]; smi = Zi_[km]; }
        if (kp > 512) { spr = Zr_[511]; spi = -Zi_[511]; } else { spr = Zr_[kp]; spi = Zi_[kp]; }
        float zr = 0.5f * Zr_[k] - 0.25f * (smr + spr);
        float zi = 0.5f * Zi_[k] - 0.25f * (smi + spi);
        Zo[k] = f2bf(zr);
        if (k >= 1 && k <= 511) Zo[512 + k] = f2bf(zi);
    }
}

// ---- elemB: phase combine C_k(g) = sum_d i^{dk} Z'_k(g-d) (LDS-staged) ------
__global__ __launch_bounds__(256) void elem_b_k(
    const ushort* __restrict__ Z, ushort* __restrict__ C) {
    __shared__ ushort Zl[4096];          // rows g-3..g (row idx = f-(g-3), d = 3-row)
    int bid = blockIdx.x;                // NB*NCOL
    int b = bid >> 12, j = bid & 4095;
    int g = j + 2;
    const ushort* Zb = Z + (long)b * NZROW * 1024;
    ushort* Cr = C + ((long)(b * NCOL + j) << 10);
    const int tid = threadIdx.x;
    const int f0 = g - 3;

    #pragma unroll
    for (int v = 0; v < 2; ++v) {
        int idx = (v << 8) + tid;        // uint4 index, 128 per row
        int row = idx >> 7;
        int f = f0 + row;
        uint4 val = make_uint4(0, 0, 0, 0);
        if (f >= 0 && f < NFR)
            val = ((const uint4*)(Zb + ((long)f << 10)))[idx & 127];
        ((uint4*)Zl)[idx] = val;
    }
    __syncthreads();

    #pragma unroll
    for (int half = 0; half < 3; ++half) {
        int k = (half < 2) ? (half << 8) + tid : 512;
        if (half == 2 && tid != 0) continue;
        if (k > 512) continue;
        int r = k & 3;
        float cr = 0.f, ci = 0.f;
        #pragma unroll
        for (int d = 0; d < 4; ++d) {
            int row = 3 - d;             // frame g-d
            float zr = bf2f(Zl[(row << 10) + k]);
            float zi = (k >= 1 && k <= 511) ? bf2f(Zl[(row << 10) + 512 + k]) : 0.f;
            int rd = (d * r) & 3;
            if      (rd == 0) { cr += zr; ci += zi; }
            else if (rd == 1) { cr -= zi; ci += zr; }
            else if (rd == 2) { cr -= zr; ci -= zi; }
            else              { cr += zi; ci -= zr; }
        }
        Cr[k] = f2bf(cr);
        if (k >= 1 && k <= 511) Cr[512 + k] = f2bf(ci);
    }
}

// ---- K6: GEMM-C (M=256 h, K=1024 ch, N=4096 segs) ---------------------------
__global__ __launch_bounds__(512) void gemm_c_k(
    const ushort* __restrict__ invT2, const ushort* __restrict__ C,
    float* __restrict__ out) {
    __shared__ char smem[49152];
    const int tid = threadIdx.x;
    const int wid = tid >> 6, lane = tid & 63;
    const int lh = lane & 15, lg = lane >> 4;
    const int g = wid >> 2;
    const int wid2 = wid & 3;
    const int wm = wid2 >> 1, wn = wid2 & 1;
    const int tg = tid & 255;
    int w = (blockIdx.x & 7) * 64 + (blockIdx.x >> 3);    // 512 = 8*64
    const int h0  = (w & 1) << 7;
    const int j0  = ((w >> 1) & 63) << 6;
    const int fo0 = 2 + j0;
    const int b   = w >> 7;
    const ushort* Cb = C + (long)b * NCOL * 1024;
    char* sm = smem + g * 24576;
    f32x4 acc[4][2] = {};

    for (int k0s = 0; k0s < 512; k0s += 64) {
        if (k0s) __syncthreads();
        int kk = (g << 9) + k0s;
        #pragma unroll
        for (int i = 0; i < 4; ++i) {
            int ci = (i << 8) + tg;
            int row = ci >> 3;
            int swz = (((ci & 7) ^ (row & 7)) << 3);
            __builtin_amdgcn_global_load_lds(
                (const AS1 unsigned int*)(invT2 + ((h0 + row) << 10) + kk + swz),
                (AS3 unsigned int*)(sm + (i << 12) + (wid2 << 10)), 16, 0, 0);
        }
        #pragma unroll
        for (int i = 0; i < 2; ++i) {
            int ci = (i << 8) + tg;
            int row = ci >> 3;
            int swz = (((ci & 7) ^ (row & 7)) << 3);
            __builtin_amdgcn_global_load_lds(
                (const AS1 unsigned int*)(Cb + ((long)(j0 + row) << 10) + kk + swz),
                (AS3 unsigned int*)(sm + 16384 + (i << 12) + (wid2 << 10)), 16, 0, 0);
        }
        __syncthreads();
        #pragma unroll
        for (int s = 0; s < 2; ++s) {
            bf16x8 av[4], bv[2];
            #pragma unroll
            for (int i = 0; i < 4; ++i) {
                int r = (wm << 6) + (i << 4) + lh;
                av[i] = *(const bf16x8*)(sm + (r << 7) + ((((s << 2) + lg) ^ (r & 7)) << 4));
            }
            #pragma unroll
            for (int j = 0; j < 2; ++j) {
                int rq = (wn << 5) + (j << 4) + lh;
                bv[j] = *(const bf16x8*)(sm + 16384 + (rq << 7) + ((((s << 2) + lg) ^ (rq & 7)) << 4));
            }
            #pragma unroll
            for (int i = 0; i < 4; ++i)
                #pragma unroll
                for (int j = 0; j < 2; ++j)
                    acc[i][j] = __builtin_amdgcn_mfma_f32_16x16x32_bf16(av[i], bv[j], acc[i][j], 0, 0, 0);
        }
    }
    __syncthreads();
    float* red = (float*)smem;
    if (g == 1) {
        #pragma unroll
        for (int i = 0; i < 4; ++i)
            #pragma unroll
            for (int j = 0; j < 2; ++j) {
                int hl = (wm << 6) + (i << 4) + (lg << 2);
                int fl = (wn << 5) + (j << 4) + lh;
                #pragma unroll
                for (int q = 0; q < 4; ++q)
                    red[(hl + q) * 64 + fl] = acc[i][j][q];
            }
    }
    __syncthreads();
    if (g == 1) return;
    float* ob = out + (long)b * LAUD;
    const float CST = 6.135923151542565e-3f;
    #pragma unroll
    for (int i = 0; i < 4; ++i) {
        int hbase = h0 + (wm << 6) + (i << 4) + (lg << 2);
        int hl = (wm << 6) + (i << 4) + (lg << 2);
        #pragma unroll
        for (int j = 0; j < 2; ++j) {
            int fo = fo0 + (wn << 5) + (j << 4) + lh;
            int fl = (wn << 5) + (j << 4) + lh;
            f32x4 v = acc[i][j];
            #pragma unroll
            for (int q = 0; q < 4; ++q) v[q] += red[(hl + q) * 64 + fl];
            if (fo == 2 || fo == 4097) {
                #pragma unroll
                for (int q = 0; q < 4; ++q) {
                    int n = (fo == 2) ? (hbase + q + 768) : (hbase + q);
                    float w2 = 0.5f - 0.5f * cosf(CST * (float)n);
                    v[q] = v[q] * (1.0f / (1.5f - w2 * w2));
                }
            } else {
                v *= (2.0f / 3.0f);
            }
            *(f32x4*)(ob + (((long)(fo - 2)) << 8) + hbase) = v;
        }
    }
}

extern "C" void kernel_launch(void* const* d_in, const int* in_sizes, int n_in,
                              void* d_out, int out_size, void* d_ws, size_t ws_size,
                              hipStream_t stream) {
    const float* audio = (const float*)d_in[0];
    const float* bias  = (const float*)d_in[1];
    float* out = (float*)d_out;
    char* wsb = (char*)d_ws;

    ushort* fwdT  = (ushort*)(wsb);
    ushort* invT2 = (ushort*)(wsb + 524288);
    ushort* aud   = (ushort*)(wsb + 1048576);
    ushort* T     = (ushort*)(wsb + 9707520);
    ushort* Z     = (ushort*)(wsb + 44310528);
    ushort* C     = (ushort*)(wsb + 77897728);

    build_bases_k<<<1024, 256, 0, stream>>>(fwdT, invT2);

    int cvt_total = NB * (ABLEN / 8);
    cvt_audio_k<<<(cvt_total + 255) / 256, 256, 0, stream>>>(audio, aud);

    gemm_t_k<<<1056, 256, 0, stream>>>(fwdT, aud, T);

    elem_a_k<<<NB * NFR, 256, 0, stream>>>(T, bias, Z);

    elem_b_k<<<NB * NCOL, 256, 0, stream>>>(Z, C);

    gemm_c_k<<<512, 512, 0, stream>>>(invT2, C, out);
}

// Round 16
// 115.821 us; speedup vs baseline: 1.7279x; 1.0036x over previous
//
#include <hip/hip_runtime.h>
#include <math.h>

// Denoiser via hop-aligned DFT factorization (N=1024, HOP=256 -> 4 segments):
//   T_k(g)  = sum_{h<256} x[g*256+h] e^{-i*th*k*h}          (GEMM-T, K=256)
//   X_k(f)  = sum_d (-i)^{dk} T_k(f+d)                      (elemA)
//   Xw_k    = 0.5 X_k - 0.25(X_{k-1}+X_{k+1})               (hann in freq)
//   Z_k     = nonlin(Xw_k);  Z'_k = 0.5 Z_k - 0.25(Z_{k-1}+Z_{k+1})  (elemA)
//   C_k(g)  = sum_d i^{dk} Z'_k(g-d), frames outside [0,4097) zero   (elemB)
//   out[g*256+h] = (1/ws) sum_k d_k [Cre cos(th k h) - Cim sin(th k h)] (GEMM-C)
// Channel map everywhere: ch<513 = re_k ; ch=512+k = im_k (k=1..511).
// elemA/elemB process 8 rows per block from an 11-row staged panel and are
// XCD-swizzled so panel overlap between neighbor blocks hits the same L2.
//
// Workspace (bytes):
//   fwdT  @ 0          : 1024*256*2  = 0.5 MB
//   invT2 @ 524,288    : 256*1024*2  = 0.5 MB
//   aud   @ 1,048,576  : 4*1,082,368*2 = 8.66 MB
//   T     @ 9,707,520  : 4*4224*1024*2 = 34.6 MB
//   Z     @ 44,310,528 : 4*4100*1024*2 = 33.6 MB   (holds Z')
//   C     @ 77,897,728 : 4*4096*1024*2 = 33.6 MB   (ends ~111.5 MB)

#define NFFT 1024
#define HOP  256
#define CUT  513
#define NB   4
#define LAUD 1048576
#define NFR  4097      // valid frames
#define NSEG 4224      // T rows per batch
#define NZROW 4100     // Z row region per batch
#define NCOL 4096      // C rows per batch = output segments (g-2)
#define ABLEN 1082368

typedef __attribute__((ext_vector_type(4))) float f32x4;
typedef __attribute__((ext_vector_type(8))) short bf16x8;

#define AS1 __attribute__((address_space(1)))
#define AS3 __attribute__((address_space(3)))

__device__ __forceinline__ unsigned short f2bf(float x) {
    unsigned u = __float_as_uint(x);
    u += 0x7FFF + ((u >> 16) & 1);   // RNE
    return (unsigned short)(u >> 16);
}
__device__ __forceinline__ float bf2f(unsigned short h) {
    return __uint_as_float(((unsigned)h) << 16);
}

// ---- K1: small bases --------------------------------------------------------
__global__ __launch_bounds__(256) void build_bases_k(
    ushort* __restrict__ fwdT, ushort* __restrict__ invT2) {
    __shared__ float ctab[1024];
    const int tid = threadIdx.x, bx = blockIdx.x;   // grid 1024
    const float CST = 6.135923151542565e-3f;        // 2*pi/1024
    #pragma unroll
    for (int i = 0; i < 4; ++i) ctab[(i << 8) + tid] = cosf(CST * (float)((i << 8) + tid));
    __syncthreads();
    int idx = (bx << 8) + tid;                      // [0, 262144)
    {   // fwdT[ch][h] : re -> cos, im -> -sin
        int ch = idx >> 8, h = idx & 255;
        int k = (ch < CUT) ? ch : ch - 512;
        int m = (k * h) & 1023;
        float base = (ch < CUT) ? ctab[m] : -ctab[(m + 768) & 1023];
        fwdT[idx] = f2bf(base);
    }
    {   // invT2[h][ch] : d_k * (re -> cos, im -> -sin)
        int h = idx >> 10, ch = idx & 1023;
        int k = (ch < CUT) ? ch : ch - 512;
        int m = (k * h) & 1023;
        float base = (ch < CUT) ? ctab[m] : -ctab[(m + 768) & 1023];
        float d = (k == 0 || k == 512) ? (1.0f / 1024.0f) : (2.0f / 1024.0f);
        invT2[idx] = f2bf(base * d);
    }
}

// ---- K2: pad+cast audio -----------------------------------------------------
__global__ void cvt_audio_k(const float* __restrict__ audio, ushort* __restrict__ aud) {
    const int NV = ABLEN / 8;                      // 135296
    int idx = blockIdx.x * blockDim.x + threadIdx.x;
    if (idx >= NB * NV) return;
    int b = idx / NV;
    int t8 = (idx - b * NV) << 3;
    const float* ap = audio + (long)b * LAUD;
    ushort o[8];
    int j0 = t8 - 512;
    if (j0 >= 0 && j0 + 7 < LAUD) {
        f32x4 v0 = *(const f32x4*)(ap + j0);
        f32x4 v1 = *(const f32x4*)(ap + j0 + 4);
        #pragma unroll
        for (int q = 0; q < 4; ++q) { o[q] = f2bf(v0[q]); o[4 + q] = f2bf(v1[q]); }
    } else {
        #pragma unroll
        for (int q = 0; q < 8; ++q) {
            int t = t8 + q;
            float v = 0.f;
            if (t < LAUD + 1024) {
                int j = t - 512;
                if (j < 0) j = -j;
                if (j >= LAUD) j = 2 * LAUD - 2 - j;
                v = ap[j];
            }
            o[q] = f2bf(v);
        }
    }
    *(ushort4*)(aud + (long)b * ABLEN + t8)     = *(ushort4*)&o[0];
    *(ushort4*)(aud + (long)b * ABLEN + t8 + 4) = *(ushort4*)&o[4];
}

// ---- K3: GEMM-T (M=1024 ch, K=256, N=4224 segs) -----------------------------
__global__ __launch_bounds__(256) void gemm_t_k(
    const ushort* __restrict__ fwdT, const ushort* __restrict__ aud,
    ushort* __restrict__ T) {
    __shared__ char smem[32768];
    const int tid = threadIdx.x;
    const int wid = tid >> 6, lane = tid & 63;
    const int lh = lane & 15, lg = lane >> 4;
    const int wm = wid >> 1, wn = wid & 1;
    int w = (blockIdx.x & 7) * 132 + (blockIdx.x >> 3);   // 1056 = 8*132
    const int f0 = (w % 33) << 7;
    const int c0 = ((w / 33) & 7) << 7;
    const int b  = w / 264;
    const ushort* ab = aud + (long)b * ABLEN;
    f32x4 acc[4][4] = {};

    for (int k0 = 0; k0 < 256; k0 += 64) {
        if (k0) __syncthreads();
        #pragma unroll
        for (int i = 0; i < 4; ++i) {
            int ci = (i << 8) + tid;
            int row = ci >> 3;
            int ks = k0 + (((ci & 7) ^ (row & 7)) << 3);
            __builtin_amdgcn_global_load_lds(
                (const AS1 unsigned int*)(fwdT + ((c0 + row) << 8) + ks),
                (AS3 unsigned int*)(smem + (i << 12) + (wid << 10)), 16, 0, 0);
            __builtin_amdgcn_global_load_lds(
                (const AS1 unsigned int*)(ab + (f0 + row) * 256 + ks),
                (AS3 unsigned int*)(smem + 16384 + (i << 12) + (wid << 10)), 16, 0, 0);
        }
        __syncthreads();
        #pragma unroll
        for (int s = 0; s < 2; ++s) {
            bf16x8 av[4], bv[4];
            #pragma unroll
            for (int i = 0; i < 4; ++i) {
                int r = (wm << 6) + (i << 4) + lh;
                av[i] = *(const bf16x8*)(smem + (r << 7) + ((((s << 2) + lg) ^ (r & 7)) << 4));
                int q = (wn << 6) + (i << 4) + lh;
                bv[i] = *(const bf16x8*)(smem + 16384 + (q << 7) + ((((s << 2) + lg) ^ (q & 7)) << 4));
            }
            #pragma unroll
            for (int i = 0; i < 4; ++i)
                #pragma unroll
                for (int j = 0; j < 4; ++j)
                    acc[i][j] = __builtin_amdgcn_mfma_f32_16x16x32_bf16(av[i], bv[j], acc[i][j], 0, 0, 0);
        }
    }
    ushort* Tb = T + (long)b * NSEG * 1024;
    #pragma unroll
    for (int i = 0; i < 4; ++i) {
        int c = c0 + (wm << 6) + (i << 4) + (lg << 2);
        #pragma unroll
        for (int j = 0; j < 4; ++j) {
            int g = f0 + (wn << 6) + (j << 4) + lh;
            ushort4 o;
            o.x = f2bf(acc[i][j][0]); o.y = f2bf(acc[i][j][1]);
            o.z = f2bf(acc[i][j][2]); o.w = f2bf(acc[i][j][3]);
            *(ushort4*)(Tb + ((long)g << 10) + c) = o;
        }
    }
}

// ---- elemA: 8 frames/block; combine + window + nonlin + synth window -> Z' --
__global__ __launch_bounds__(256) void elem_a_k(
    const ushort* __restrict__ T, const float* __restrict__ bias,
    ushort* __restrict__ Z) {
    __shared__ ushort Tl[11 * 1024];     // rows f0 .. f0+10 (22.5 KB)
    __shared__ float Xr[513], Xi[513], Zr_[513], Zi_[513];
    // bijective XCD swizzle: n = NB*513 = 2052 = 8q+r, q=256 r=4
    int bid = blockIdx.x;
    int x = bid & 7, s = bid >> 3;
    int w = (x < 4) ? x * 257 + s : 1028 + (x - 4) * 256 + s;
    int b = w / 513, fblk = w - b * 513;
    int f0 = fblk << 3;
    const ushort* Tb = T + (long)b * NSEG * 1024;
    ushort* Zb = Z + (long)b * NZROW * 1024;
    const int tid = threadIdx.x;

    const uint4* src = (const uint4*)(Tb + ((long)f0 << 10));   // 1408 uint4
    #pragma unroll
    for (int i = 0; i < 6; ++i) {
        int idx = (i << 8) + tid;
        if (idx < 1408) ((uint4*)Tl)[idx] = src[idx];
    }
    __syncthreads();

    for (int fi = 0; fi < 8; ++fi) {
        int f = f0 + fi;
        if (f >= NFR) break;
        // phase 1: X_k = sum_d (-i)^{dk} T_k(f+d)
        #pragma unroll
        for (int half = 0; half < 2; ++half) {
            int k = (half << 8) + tid;           // 0..511
            float a[4], bb[4];
            #pragma unroll
            for (int d = 0; d < 4; ++d) {
                a[d]  = bf2f(Tl[((fi + d) << 10) + k]);
                bb[d] = (k >= 1) ? bf2f(Tl[((fi + d) << 10) + 512 + k]) : 0.f;
            }
            int r = k & 3;
            float xr, xi;
            if      (r == 0) { xr = a[0] + a[1] + a[2] + a[3];   xi = bb[0] + bb[1] + bb[2] + bb[3]; }
            else if (r == 1) { xr = a[0] + bb[1] - a[2] - bb[3]; xi = bb[0] - a[1] - bb[2] + a[3]; }
            else if (r == 2) { xr = a[0] - a[1] + a[2] - a[3];   xi = bb[0] - bb[1] + bb[2] - bb[3]; }
            else             { xr = a[0] - bb[1] - a[2] + bb[3]; xi = bb[0] + a[1] - bb[2] - a[3]; }
            Xr[k] = xr; Xi[k] = xi;
        }
        if (tid == 0) {                          // k = 512 (512&3 == 0 -> all +)
            Xr[512] = bf2f(Tl[(fi << 10) + 512]) + bf2f(Tl[((fi + 1) << 10) + 512])
                    + bf2f(Tl[((fi + 2) << 10) + 512]) + bf2f(Tl[((fi + 3) << 10) + 512]);
            Xi[512] = 0.f;
        }
        __syncthreads();
        // phase 2: window + nonlin
        #pragma unroll
        for (int half = 0; half < 3; ++half) {
            int k = (half < 2) ? (half << 8) + tid : 512;
            if (half == 2 && tid != 0) continue;
            int km = k - 1, kp = k + 1;
            float smr, smi, spr, spi;
            if (km < 0)   { smr = Xr[1];   smi = -Xi[1]; }   else { smr = Xr[km]; smi = Xi[km]; }
            if (kp > 512) { spr = Xr[511]; spi = -Xi[511]; } else { spr = Xr[kp]; spi = Xi[kp]; }
            float xwr = 0.5f * Xr[k] - 0.25f * (smr + spr);
            float xwi = 0.5f * Xi[k] - 0.25f * (smi + spi);
            float mag = sqrtf(xwr * xwr + xwi * xwi);
            float sc = mag > 0.f ? fmaxf(mag - 0.1f * bias[k], 0.f) / mag : 0.f;
            Zr_[k] = xwr * sc; Zi_[k] = xwi * sc;
        }
        __syncthreads();
        // phase 3: synth window, store bf16
        ushort* Zo = Zb + ((long)f << 10);
        #pragma unroll
        for (int half = 0; half < 3; ++half) {
            int k = (half < 2) ? (half << 8) + tid : 512;
            if (half == 2 && tid != 0) continue;
            int km = k - 1, kp = k + 1;
            float smr, smi, spr, spi;
            if (km < 0)   { smr = Zr_[1];   smi = -Zi_[1]; }   else { smr = Zr_[km]; smi = Zi_[km]; }
            if (kp > 512) { spr = Zr_[511]; spi = -Zi_[511]; } else { spr = Zr_[kp]; spi = Zi_[kp]; }
            float zr = 0.5f * Zr_[k] - 0.25f * (smr + spr);
            float zi = 0.5f * Zi_[k] - 0.25f * (smi + spi);
            Zo[k] = f2bf(zr);
            if (k >= 1 && k <= 511) Zo[512 + k] = f2bf(zi);
        }
        __syncthreads();   // Zr_/Xr reuse guard for next frame
    }
}

// ---- elemB: 8 outputs/block; C_k(g) = sum_d i^{dk} Z'_k(g-d) ----------------
__global__ __launch_bounds__(256) void elem_b_k(
    const ushort* __restrict__ Z, ushort* __restrict__ C) {
    __shared__ ushort Zl[11 * 1024];     // rows g0-3 .. g0+7
    // bijective XCD swizzle: n = 2048 = 8*256
    int bid = blockIdx.x;
    int w = (bid & 7) * 256 + (bid >> 3);
    int b = w >> 9, gblk = w & 511;
    int g0 = 2 + (gblk << 3);
    const ushort* Zb = Z + (long)b * NZROW * 1024;
    ushort* Cb = C + (long)b * NCOL * 1024;
    const int tid = threadIdx.x;
    const int fbase = g0 - 3;

    #pragma unroll
    for (int i = 0; i < 6; ++i) {
        int idx = (i << 8) + tid;        // uint4 units, 128 per row
        if (idx < 1408) {
            int row = idx >> 7;
            int f = fbase + row;
            uint4 v = make_uint4(0, 0, 0, 0);
            if (f >= 0 && f < NFR)
                v = ((const uint4*)(Zb + ((long)f << 10)))[idx & 127];
            ((uint4*)Zl)[idx] = v;
        }
    }
    __syncthreads();

    for (int gi = 0; gi < 8; ++gi) {
        ushort* Cr = Cb + ((long)(g0 + gi - 2) << 10);
        #pragma unroll
        for (int half = 0; half < 2; ++half) {
            int k = (half << 8) + tid;   // 0..511
            int r = k & 3;
            float cr = 0.f, ci = 0.f;
            #pragma unroll
            for (int d = 0; d < 4; ++d) {
                int row = gi + 3 - d;    // frame g-d
                float zr = bf2f(Zl[(row << 10) + k]);
                float zi = (k >= 1) ? bf2f(Zl[(row << 10) + 512 + k]) : 0.f;
                int rd = (d * r) & 3;
                if      (rd == 0) { cr += zr; ci += zi; }
                else if (rd == 1) { cr -= zi; ci += zr; }
                else if (rd == 2) { cr -= zr; ci -= zi; }
                else              { cr += zi; ci -= zr; }
            }
            Cr[k] = f2bf(cr);
            if (k >= 1) Cr[512 + k] = f2bf(ci);
        }
        if (tid == 0) {                  // k=512: r=0 -> all +
            float cr = bf2f(Zl[((gi + 3) << 10) + 512]) + bf2f(Zl[((gi + 2) << 10) + 512])
                     + bf2f(Zl[((gi + 1) << 10) + 512]) + bf2f(Zl[(gi << 10) + 512]);
            Cr[512] = f2bf(cr);
        }
    }
}

// ---- K6: GEMM-C (M=256 h, K=1024 ch, N=4096 segs) ---------------------------
__global__ __launch_bounds__(512) void gemm_c_k(
    const ushort* __restrict__ invT2, const ushort* __restrict__ C,
    float* __restrict__ out) {
    __shared__ char smem[49152];
    const int tid = threadIdx.x;
    const int wid = tid >> 6, lane = tid & 63;
    const int lh = lane & 15, lg = lane >> 4;
    const int g = wid >> 2;
    const int wid2 = wid & 3;
    const int wm = wid2 >> 1, wn = wid2 & 1;
    const int tg = tid & 255;
    int w = (blockIdx.x & 7) * 64 + (blockIdx.x >> 3);    // 512 = 8*64
    const int h0  = (w & 1) << 7;
    const int j0  = ((w >> 1) & 63) << 6;
    const int fo0 = 2 + j0;
    const int b   = w >> 7;
    const ushort* Cb = C + (long)b * NCOL * 1024;
    char* sm = smem + g * 24576;
    f32x4 acc[4][2] = {};

    for (int k0s = 0; k0s < 512; k0s += 64) {
        if (k0s) __syncthreads();
        int kk = (g << 9) + k0s;
        #pragma unroll
        for (int i = 0; i < 4; ++i) {
            int ci = (i << 8) + tg;
            int row = ci >> 3;
            int swz = (((ci & 7) ^ (row & 7)) << 3);
            __builtin_amdgcn_global_load_lds(
                (const AS1 unsigned int*)(invT2 + ((h0 + row) << 10) + kk + swz),
                (AS3 unsigned int*)(sm + (i << 12) + (wid2 << 10)), 16, 0, 0);
        }
        #pragma unroll
        for (int i = 0; i < 2; ++i) {
            int ci = (i << 8) + tg;
            int row = ci >> 3;
            int swz = (((ci & 7) ^ (row & 7)) << 3);
            __builtin_amdgcn_global_load_lds(
                (const AS1 unsigned int*)(Cb + ((long)(j0 + row) << 10) + kk + swz),
                (AS3 unsigned int*)(sm + 16384 + (i << 12) + (wid2 << 10)), 16, 0, 0);
        }
        __syncthreads();
        #pragma unroll
        for (int s = 0; s < 2; ++s) {
            bf16x8 av[4], bv[2];
            #pragma unroll
            for (int i = 0; i < 4; ++i) {
                int r = (wm << 6) + (i << 4) + lh;
                av[i] = *(const bf16x8*)(sm + (r << 7) + ((((s << 2) + lg) ^ (r & 7)) << 4));
            }
            #pragma unroll
            for (int j = 0; j < 2; ++j) {
                int rq = (wn << 5) + (j << 4) + lh;
                bv[j] = *(const bf16x8*)(sm + 16384 + (rq << 7) + ((((s << 2) + lg) ^ (rq & 7)) << 4));
            }
            #pragma unroll
            for (int i = 0; i < 4; ++i)
                #pragma unroll
                for (int j = 0; j < 2; ++j)
                    acc[i][j] = __builtin_amdgcn_mfma_f32_16x16x32_bf16(av[i], bv[j], acc[i][j], 0, 0, 0);
        }
    }
    __syncthreads();
    float* red = (float*)smem;
    if (g == 1) {
        #pragma unroll
        for (int i = 0; i < 4; ++i)
            #pragma unroll
            for (int j = 0; j < 2; ++j) {
                int hl = (wm << 6) + (i << 4) + (lg << 2);
                int fl = (wn << 5) + (j << 4) + lh;
                #pragma unroll
                for (int q = 0; q < 4; ++q)
                    red[(hl + q) * 64 + fl] = acc[i][j][q];
            }
    }
    __syncthreads();
    if (g == 1) return;
    float* ob = out + (long)b * LAUD;
    const float CST = 6.135923151542565e-3f;
    #pragma unroll
    for (int i = 0; i < 4; ++i) {
        int hbase = h0 + (wm << 6) + (i << 4) + (lg << 2);
        int hl = (wm << 6) + (i << 4) + (lg << 2);
        #pragma unroll
        for (int j = 0; j < 2; ++j) {
            int fo = fo0 + (wn << 5) + (j << 4) + lh;
            int fl = (wn << 5) + (j << 4) + lh;
            f32x4 v = acc[i][j];
            #pragma unroll
            for (int q = 0; q < 4; ++q) v[q] += red[(hl + q) * 64 + fl];
            if (fo == 2 || fo == 4097) {
                #pragma unroll
                for (int q = 0; q < 4; ++q) {
                    int n = (fo == 2) ? (hbase + q + 768) : (hbase + q);
                    float w2 = 0.5f - 0.5f * cosf(CST * (float)n);
                    v[q] = v[q] * (1.0f / (1.5f - w2 * w2));
                }
            } else {
                v *= (2.0f / 3.0f);
            }
            *(f32x4*)(ob + (((long)(fo - 2)) << 8) + hbase) = v;
        }
    }
}

extern "C" void kernel_launch(void* const* d_in, const int* in_sizes, int n_in,
                              void* d_out, int out_size, void* d_ws, size_t ws_size,
                              hipStream_t stream) {
    const float* audio = (const float*)d_in[0];
    const float* bias  = (const float*)d_in[1];
    float* out = (float*)d_out;
    char* wsb = (char*)d_ws;

    ushort* fwdT  = (ushort*)(wsb);
    ushort* invT2 = (ushort*)(wsb + 524288);
    ushort* aud   = (ushort*)(wsb + 1048576);
    ushort* T     = (ushort*)(wsb + 9707520);
    ushort* Z     = (ushort*)(wsb + 44310528);
    ushort* C     = (ushort*)(wsb + 77897728);

    build_bases_k<<<1024, 256, 0, stream>>>(fwdT, invT2);

    int cvt_total = NB * (ABLEN / 8);
    cvt_audio_k<<<(cvt_total + 255) / 256, 256, 0, stream>>>(audio, aud);

    gemm_t_k<<<1056, 256, 0, stream>>>(fwdT, aud, T);

    elem_a_k<<<2052, 256, 0, stream>>>(T, bias, Z);

    elem_b_k<<<2048, 256, 0, stream>>>(Z, C);

    gemm_c_k<<<512, 512, 0, stream>>>(invT2, C, out);
}